// Round 15
// baseline (116.814 us; speedup 1.0000x reference)
//
#include <hip/hip_runtime.h>
#include <hip/hip_bf16.h>
#include <hip/hip_cooperative_groups.h>

namespace cg = cooperative_groups;

// Problem constants (fixed by reference): B=8, T=2048, C=64
#define B_ 8
#define T_ 2048
#define LOG2E 1.4426950408889634f

typedef _Float16 half8 __attribute__((ext_vector_type(8)));
typedef _Float16 half4 __attribute__((ext_vector_type(4)));
typedef float f32x4 __attribute__((ext_vector_type(4)));

#define MFMA16(A, Bv, Cv) __builtin_amdgcn_mfma_f32_16x16x32_f16((A), (Bv), (Cv), 0, 0, 0)

__device__ inline float xexp2(float x)
{
    float r;
    asm("v_exp_f32 %0, %1" : "=v"(r) : "v"(x));
    return r;
}

// lane-local max of the 8 scores
#define PMAX(s0, s1)                                                         \
    fmaxf(fmaxf(fmaxf(fmaxf(s0[0], s0[1]), s0[2]),                           \
                fmaxf(fmaxf(s0[3], s1[0]), s1[1])),                          \
          fmaxf(s1[2], s1[3]))

// full reduce + rescale for one tile (inside the rare combined branch)
#define RESC(pm, mr, ls, a0, a1, a2, a3)                                     \
    do {                                                                     \
        float pmw = fmaxf(pm, __shfl_xor(pm, 16));                           \
        pmw = fmaxf(pmw, __shfl_xor(pmw, 32));                               \
        const float mnew = fmaxf(mr, pmw);                                   \
        const float fac  = xexp2(mr - mnew);                                 \
        mr = mnew;                                                           \
        ls *= fac;                                                           \
        const int lg = 4 * ((threadIdx.x & 63) >> 4);                        \
        const int lb = (threadIdx.x & 48);                                   \
        const float f0 = __shfl(fac, lb | (lg + 0));                         \
        const float f1 = __shfl(fac, lb | (lg + 1));                         \
        const float f2 = __shfl(fac, lb | (lg + 2));                         \
        const float f3 = __shfl(fac, lb | (lg + 3));                         \
        a0[0] *= f0; a0[1] *= f1; a0[2] *= f2; a0[3] *= f3;                  \
        a1[0] *= f0; a1[1] *= f1; a1[2] *= f2; a1[3] *= f3;                  \
        a2[0] *= f0; a2[1] *= f1; a2[2] *= f2; a2[3] *= f3;                  \
        a3[0] *= f0; a3[1] *= f1; a3[2] *= f2; a3[3] *= f3;                  \
    } while (0)

// exp2 + lsum + f16 pack for one tile (branch-free)
#define EXPPACK(s0, s1, mr, ls, pav)                                         \
    do {                                                                     \
        const float e0 = xexp2(s0[0] - mr), e1 = xexp2(s0[1] - mr);          \
        const float e2 = xexp2(s0[2] - mr), e3 = xexp2(s0[3] - mr);          \
        const float e4 = xexp2(s1[0] - mr), e5 = xexp2(s1[1] - mr);          \
        const float e6 = xexp2(s1[2] - mr), e7 = xexp2(s1[3] - mr);          \
        ls += ((e0 + e1) + (e2 + e3)) + ((e4 + e5) + (e6 + e7));             \
        pav[0] = (_Float16)e0; pav[1] = (_Float16)e1;                        \
        pav[2] = (_Float16)e2; pav[3] = (_Float16)e3;                        \
        pav[4] = (_Float16)e4; pav[5] = (_Float16)e5;                        \
        pav[6] = (_Float16)e6; pav[7] = (_Float16)e7;                        \
    } while (0)

// ---------------------------------------------------------------------------
// FUSED kernel (cooperative): Phase 1 = projections into fragment-major
// Q/K/V (R14-verified layouts; each wave does 2 (rt,dt) units), grid.sync(),
// Phase 2 = flash attention with FULLY stage-clustered inner loop:
// 16 QK^T MFMA -> 4 lane-local maxima -> ONE combined trigger branch ->
// 32 clustered exp2 + 4 packs -> 16 clustered PV MFMA. Fences/iter: 4 -> 1.
// Grid = 256 blocks x 512 thr = 1 block/CU (LDS 139 KB) -- co-resident.
// ---------------------------------------------------------------------------
__global__ __launch_bounds__(512, 1) void fused_kernel(
    const float* __restrict__ F, const float* __restrict__ WM,
    const float* __restrict__ WN, const float* __restrict__ WV,
    _Float16* __restrict__ Qf, _Float16* __restrict__ Kf,
    _Float16* __restrict__ Vf, float* __restrict__ out)
{
    __shared__ float Ol[8][64][68];    // 139 KB: [split][row][d]
    __shared__ float Ml[8][64];
    __shared__ float Ll[8][64];

    const int lane = threadIdx.x & 63;
    const int wid  = threadIdx.x >> 6;           // 0..7
    const int blk  = blockIdx.x;                 // 0..255
    const int b    = blk & 7;                    // XCD-affine batch
    const int tile = blk >> 3;                   // 0..31
    const int ql = lane & 15;
    const int g  = lane >> 4;

    // ======================= Phase 1: projections =======================
    {
        const int rt = tile * 4 + (wid & 3);      // row-tile within batch
        const int rowbase = b * T_ + rt * 16;

        // F fragments (shared by both dt units of this wave)
        const float* fr = F + (size_t)(rowbase + ql) * 64;
        const f32x4 v00 = *(const f32x4*)(fr + 8 * g);
        const f32x4 v01 = *(const f32x4*)(fr + 8 * g + 4);
        const f32x4 v10 = *(const f32x4*)(fr + 32 + 8 * g);
        const f32x4 v11 = *(const f32x4*)(fr + 32 + 8 * g + 4);
        half8 af0, af1;
#pragma unroll
        for (int j = 0; j < 4; ++j) {
            af0[j]     = (_Float16)v00[j];
            af0[4 + j] = (_Float16)v01[j];
            af1[j]     = (_Float16)v10[j];
            af1[4 + j] = (_Float16)v11[j];
        }

#pragma unroll
        for (int j = 0; j < 2; ++j) {
            const int dt = ((wid >> 2) << 1) | j; // 0..3
            const int d  = dt * 16 + ql;

            half8 wq0, wq1, wk0, wk1, wv0, wv1;
#pragma unroll
            for (int jj = 0; jj < 8; ++jj) {
                const int k0 = (8 * g + jj) * 64 + d;
                const int k1 = (32 + 8 * g + jj) * 64 + d;
                wq0[jj] = (_Float16)WM[k0];
                wq1[jj] = (_Float16)WM[k1];
                wk0[jj] = (_Float16)WN[k0];
                wk1[jj] = (_Float16)WN[k1];
                wv0[jj] = (_Float16)WV[k0];
                wv1[jj] = (_Float16)WV[k1];
            }

            f32x4 z = {0.f, 0.f, 0.f, 0.f};
            f32x4 accQ = MFMA16(wq0, af0, z);     // swapped: lane=t, regs=d
            accQ = MFMA16(wq1, af1, accQ);
            f32x4 accK = MFMA16(wk0, af0, z);
            accK = MFMA16(wk1, af1, accK);
            f32x4 accV = MFMA16(af0, wv0, z);     // unswapped: lane=d, regs=key
            accV = MFMA16(af1, wv1, accV);

            const int d0 = dt * 16 + 4 * g;
            const int p  = ((d0 >> 5) << 2) | ((d0 >> 3) & 3);
            const size_t tbase =
                (((size_t)b * 128 + rt) * 8 + p) * 128 + ql * 8 + (d0 & 7);
            {
                half4 qs;
#pragma unroll
                for (int r = 0; r < 4; ++r) qs[r] = (_Float16)(accQ[r] * LOG2E);
                *(half4*)(Qf + tbase) = qs;
            }
            {
                half4 ks;
#pragma unroll
                for (int r = 0; r < 4; ++r) ks[r] = (_Float16)accK[r];
                *(half4*)(Kf + tbase) = ks;
            }
            {
                half4 vs;
#pragma unroll
                for (int r = 0; r < 4; ++r) vs[r] = (_Float16)accV[r];
                const int kt5 = rt >> 1;
                const int cp0 = 8 * g + 4 * (rt & 1);
                *(half4*)(Vf + ((((size_t)b * 64 + kt5) * 4 + dt) * 16 + ql) * 32 + cp0) = vs;
            }
        }
    }

    __threadfence();
    cg::this_grid().sync();

    // ======================= Phase 2: attention =======================
    const half8* QfB = (const half8*)Qf + (size_t)b * 16384;  // 128 tiles * 128
    const half8* KfB = (const half8*)Kf + (size_t)b * 16384;
    const half8* VfB = (const half8*)Vf + (size_t)b * 16384;  // 64 tiles * 256

    const half8* qtA = QfB + (size_t)(4 * tile + 0) * 128;
    const half8* qtB = QfB + (size_t)(4 * tile + 1) * 128;
    const half8* qtC = QfB + (size_t)(4 * tile + 2) * 128;
    const half8* qtD = QfB + (size_t)(4 * tile + 3) * 128;
    const half8 qA0 = qtA[g * 16 + ql], qA1 = qtA[(4 + g) * 16 + ql];
    const half8 qB0 = qtB[g * 16 + ql], qB1 = qtB[(4 + g) * 16 + ql];
    const half8 qC0 = qtC[g * 16 + ql], qC1 = qtC[(4 + g) * 16 + ql];
    const half8 qD0 = qtD[g * 16 + ql], qD1 = qtD[(4 + g) * 16 + ql];

    const f32x4 z4 = {0.f, 0.f, 0.f, 0.f};
    f32x4 aA0 = z4, aA1 = z4, aA2 = z4, aA3 = z4;
    f32x4 aB0 = z4, aB1 = z4, aB2 = z4, aB3 = z4;
    f32x4 aC0 = z4, aC1 = z4, aC2 = z4, aC3 = z4;
    f32x4 aD0 = z4, aD1 = z4, aD2 = z4, aD3 = z4;
    float mA = -1e30f, lsA = 0.f;
    float mB = -1e30f, lsB = 0.f;
    float mC = -1e30f, lsC = 0.f;
    float mD = -1e30f, lsD = 0.f;

    const int kb0 = wid << 8;                    // 256 keys per split
    const half8* kA = KfB + (size_t)(kb0 >> 4) * 128 + g * 16 + ql;
    const half8* vA = VfB + (size_t)(kb0 >> 5) * 256 + ql * 4 + g;

    half8 k0lo = kA[0];
    half8 k0hi = kA[64];
    half8 k1lo = kA[128];
    half8 k1hi = kA[192];
    half8 v0 = vA[0];
    half8 v1 = vA[64];
    half8 v2 = vA[128];
    half8 v3 = vA[192];

    for (int it = 0; it < 8; ++it) {
        half8 nk0lo, nk0hi, nk1lo, nk1hi, nv0, nv1, nv2, nv3;
        if (it < 7) {
            nk0lo = kA[256];
            nk0hi = kA[256 + 64];
            nk1lo = kA[256 + 128];
            nk1hi = kA[256 + 192];
            nv0 = vA[256];
            nv1 = vA[256 + 64];
            nv2 = vA[256 + 128];
            nv3 = vA[256 + 192];
        }

        // ---- QK^T phase: 16 MFMAs, branch-free ----
        f32x4 sA0 = z4, sA1 = z4, sB0 = z4, sB1 = z4;
        f32x4 sC0 = z4, sC1 = z4, sD0 = z4, sD1 = z4;
        sA0 = MFMA16(k0lo, qA0, sA0);
        sB0 = MFMA16(k0lo, qB0, sB0);
        sC0 = MFMA16(k0lo, qC0, sC0);
        sD0 = MFMA16(k0lo, qD0, sD0);
        sA1 = MFMA16(k1lo, qA0, sA1);
        sB1 = MFMA16(k1lo, qB0, sB1);
        sC1 = MFMA16(k1lo, qC0, sC1);
        sD1 = MFMA16(k1lo, qD0, sD1);
        sA0 = MFMA16(k0hi, qA1, sA0);
        sB0 = MFMA16(k0hi, qB1, sB0);
        sC0 = MFMA16(k0hi, qC1, sC0);
        sD0 = MFMA16(k0hi, qD1, sD0);
        sA1 = MFMA16(k1hi, qA1, sA1);
        sB1 = MFMA16(k1hi, qB1, sB1);
        sC1 = MFMA16(k1hi, qC1, sC1);
        sD1 = MFMA16(k1hi, qD1, sD1);

        // ---- softmax phase: ONE combined trigger branch ----
        const float pmA = PMAX(sA0, sA1);
        const float pmB = PMAX(sB0, sB1);
        const float pmC = PMAX(sC0, sC1);
        const float pmD = PMAX(sD0, sD1);
        const float trig = fmaxf(fmaxf(pmA - mA, pmB - mB),
                                 fmaxf(pmC - mC, pmD - mD));
        if (__any(trig > 8.0f)) {
            RESC(pmA, mA, lsA, aA0, aA1, aA2, aA3);
            RESC(pmB, mB, lsB, aB0, aB1, aB2, aB3);
            RESC(pmC, mC, lsC, aC0, aC1, aC2, aC3);
            RESC(pmD, mD, lsD, aD0, aD1, aD2, aD3);
        }

        // ---- clustered exp2 + pack ----
        half8 pavA, pavB, pavC, pavD;
        EXPPACK(sA0, sA1, mA, lsA, pavA);
        EXPPACK(sB0, sB1, mB, lsB, pavB);
        EXPPACK(sC0, sC1, mC, lsC, pavC);
        EXPPACK(sD0, sD1, mD, lsD, pavD);

        // ---- clustered PV: 16 MFMAs ----
        aA0 = MFMA16(pavA, v0, aA0);
        aB0 = MFMA16(pavB, v0, aB0);
        aC0 = MFMA16(pavC, v0, aC0);
        aD0 = MFMA16(pavD, v0, aD0);
        aA1 = MFMA16(pavA, v1, aA1);
        aB1 = MFMA16(pavB, v1, aB1);
        aC1 = MFMA16(pavC, v1, aC1);
        aD1 = MFMA16(pavD, v1, aD1);
        aA2 = MFMA16(pavA, v2, aA2);
        aB2 = MFMA16(pavB, v2, aB2);
        aC2 = MFMA16(pavC, v2, aC2);
        aD2 = MFMA16(pavD, v2, aD2);
        aA3 = MFMA16(pavA, v3, aA3);
        aB3 = MFMA16(pavB, v3, aB3);
        aC3 = MFMA16(pavC, v3, aC3);
        aD3 = MFMA16(pavD, v3, aD3);

        if (it < 7) {
            k0lo = nk0lo; k0hi = nk0hi; k1lo = nk1lo; k1hi = nk1hi;
            v0 = nv0; v1 = nv1; v2 = nv2; v3 = nv3;
        }
        kA += 256;
        vA += 256;
    }

    // ---- reduce per-lane lsum partials across the 4 lane-groups ----
    lsA += __shfl_xor(lsA, 16); lsA += __shfl_xor(lsA, 32);
    lsB += __shfl_xor(lsB, 16); lsB += __shfl_xor(lsB, 32);
    lsC += __shfl_xor(lsC, 16); lsC += __shfl_xor(lsC, 32);
    lsD += __shfl_xor(lsD, 16); lsD += __shfl_xor(lsD, 32);

    // ---- write partials to LDS ----
#pragma unroll
    for (int r = 0; r < 4; ++r) {
        Ol[wid][     4 * g + r][ 0 + ql] = aA0[r];
        Ol[wid][     4 * g + r][16 + ql] = aA1[r];
        Ol[wid][     4 * g + r][32 + ql] = aA2[r];
        Ol[wid][     4 * g + r][48 + ql] = aA3[r];
        Ol[wid][16 + 4 * g + r][ 0 + ql] = aB0[r];
        Ol[wid][16 + 4 * g + r][16 + ql] = aB1[r];
        Ol[wid][16 + 4 * g + r][32 + ql] = aB2[r];
        Ol[wid][16 + 4 * g + r][48 + ql] = aB3[r];
        Ol[wid][32 + 4 * g + r][ 0 + ql] = aC0[r];
        Ol[wid][32 + 4 * g + r][16 + ql] = aC1[r];
        Ol[wid][32 + 4 * g + r][32 + ql] = aC2[r];
        Ol[wid][32 + 4 * g + r][48 + ql] = aC3[r];
        Ol[wid][48 + 4 * g + r][ 0 + ql] = aD0[r];
        Ol[wid][48 + 4 * g + r][16 + ql] = aD1[r];
        Ol[wid][48 + 4 * g + r][32 + ql] = aD2[r];
        Ol[wid][48 + 4 * g + r][48 + ql] = aD3[r];
    }
    if (g == 0) {
        Ml[wid][     ql] = mA;  Ll[wid][     ql] = lsA;
        Ml[wid][16 + ql] = mB;  Ll[wid][16 + ql] = lsB;
        Ml[wid][32 + ql] = mC;  Ll[wid][32 + ql] = lsC;
        Ml[wid][48 + ql] = mD;  Ll[wid][48 + ql] = lsD;
    }
    __syncthreads();

    // ---- combine 8 key-splits; 512 threads, one (row, 8-col chunk) each ----
    const int tid = threadIdx.x;
    const int qq  = tid >> 3;                    // 0..63 row within block
    const int d0  = (tid & 7) * 8;

    float mm[8], lv[8];
#pragma unroll
    for (int s = 0; s < 8; ++s) {
        mm[s] = Ml[s][qq];
        lv[s] = Ll[s][qq];
    }
    float ms = mm[0];
#pragma unroll
    for (int s = 1; s < 8; ++s) ms = fmaxf(ms, mm[s]);
    float lt = 0.f;
    f32x4 oa = {0.f, 0.f, 0.f, 0.f};
    f32x4 ob2 = {0.f, 0.f, 0.f, 0.f};
#pragma unroll
    for (int s = 0; s < 8; ++s) {
        const float sc = xexp2(mm[s] - ms);
        lt += lv[s] * sc;
        oa  += *(const f32x4*)(&Ol[s][qq][d0])     * sc;
        ob2 += *(const f32x4*)(&Ol[s][qq][d0 + 4]) * sc;
    }
    const float inv = 1.0f / lt;
    const size_t grow = (size_t)b * T_ + (tile << 6) + qq;
    const f32x4 fr0 = *(const f32x4*)(F + grow * 64 + d0);
    const f32x4 fr1 = *(const f32x4*)(F + grow * 64 + d0 + 4);
    *(f32x4*)(out + grow * 64 + d0)     = oa * inv + fr0;
    *(f32x4*)(out + grow * 64 + d0 + 4) = ob2 * inv + fr1;
}

extern "C" void kernel_launch(void* const* d_in, const int* in_sizes, int n_in,
                              void* d_out, int out_size, void* d_ws, size_t ws_size,
                              hipStream_t stream)
{
    const float* F  = (const float*)d_in[0];
    const float* WM = (const float*)d_in[1];
    const float* WN = (const float*)d_in[2];
    const float* WV = (const float*)d_in[3];
    float* out = (float*)d_out;

    const size_t proj_bytes = (size_t)B_ * T_ * 64 * sizeof(_Float16); // 2 MB
    char* ws = (char*)d_ws;
    _Float16* Qf = (_Float16*)(ws);
    _Float16* Kf = (_Float16*)(ws + proj_bytes);
    _Float16* Vf = (_Float16*)(ws + 2 * proj_bytes);

    void* args[] = {(void*)&F, (void*)&WM, (void*)&WN, (void*)&WV,
                    (void*)&Qf, (void*)&Kf, (void*)&Vf, (void*)&out};
    hipLaunchCooperativeKernel((const void*)fused_kernel, dim3(256), dim3(512),
                               args, 0, stream);
}

// Round 16
// 26.672 us; speedup vs baseline: 4.3796x; 4.3796x over previous
//
#include <hip/hip_runtime.h>
#include <hip/hip_bf16.h>

// Problem constants (fixed by reference): B=8, T=2048, C=64
#define B_ 8
#define T_ 2048
#define LOG2E 1.4426950408889634f

typedef _Float16 half8 __attribute__((ext_vector_type(8)));
typedef _Float16 half4 __attribute__((ext_vector_type(4)));
typedef float f32x4 __attribute__((ext_vector_type(4)));

#define MFMA16(A, Bv, Cv) __builtin_amdgcn_mfma_f32_16x16x32_f16((A), (Bv), (Cv), 0, 0, 0)

__device__ inline float xexp2(float x)
{
    float r;
    asm("v_exp_f32 %0, %1" : "=v"(r) : "v"(x));
    return r;
}

// ---------------------------------------------------------------------------
// Kernel 1: MFMA projections -> fragment-major Q/K/V layouts (R14-verified,
// byte-identical). Inline W prepack from fp32; all stores 8B coalesced.
// ---------------------------------------------------------------------------
__global__ __launch_bounds__(256) void proj_kernel(
    const float* __restrict__ F, const float* __restrict__ WM,
    const float* __restrict__ WN, const float* __restrict__ WV,
    _Float16* __restrict__ Qf, _Float16* __restrict__ Kf,
    _Float16* __restrict__ Vf)
{
    const int lane = threadIdx.x & 63;
    const int dt   = threadIdx.x >> 6;            // 0..3 = d-tile
    const int ql = lane & 15;
    const int g  = lane >> 4;
    const int blk = blockIdx.x;                   // 0..1023
    const int b   = blk & 7;                      // XCD-affine batch
    const int rt  = blk >> 3;                     // 0..127 row-tile in batch
    const int rowbase = b * T_ + rt * 16;
    const int d = dt * 16 + ql;

    const float* fr = F + (size_t)(rowbase + ql) * 64;
    const f32x4 v00 = *(const f32x4*)(fr + 8 * g);
    const f32x4 v01 = *(const f32x4*)(fr + 8 * g + 4);
    const f32x4 v10 = *(const f32x4*)(fr + 32 + 8 * g);
    const f32x4 v11 = *(const f32x4*)(fr + 32 + 8 * g + 4);
    half8 af0, af1;
#pragma unroll
    for (int j = 0; j < 4; ++j) {
        af0[j]     = (_Float16)v00[j];
        af0[4 + j] = (_Float16)v01[j];
        af1[j]     = (_Float16)v10[j];
        af1[4 + j] = (_Float16)v11[j];
    }

    half8 wq0, wq1, wk0, wk1, wv0, wv1;
#pragma unroll
    for (int j = 0; j < 8; ++j) {
        const int k0 = (8 * g + j) * 64 + d;
        const int k1 = (32 + 8 * g + j) * 64 + d;
        wq0[j] = (_Float16)WM[k0];
        wq1[j] = (_Float16)WM[k1];
        wk0[j] = (_Float16)WN[k0];
        wk1[j] = (_Float16)WN[k1];
        wv0[j] = (_Float16)WV[k0];
        wv1[j] = (_Float16)WV[k1];
    }

    f32x4 z = {0.f, 0.f, 0.f, 0.f};
    // Q, K swapped: lane = t (row), regs = d
    f32x4 accQ = MFMA16(wq0, af0, z);
    accQ = MFMA16(wq1, af1, accQ);
    f32x4 accK = MFMA16(wk0, af0, z);
    accK = MFMA16(wk1, af1, accK);
    // V unswapped: lane = d, regs = key
    f32x4 accV = MFMA16(af0, wv0, z);
    accV = MFMA16(af1, wv1, accV);

    const int d0 = dt * 16 + 4 * g;
    const int p  = ((d0 >> 5) << 2) | ((d0 >> 3) & 3);
    const size_t tbase = (((size_t)b * 128 + rt) * 8 + p) * 128 + ql * 8 + (d0 & 7);
    {
        half4 qs;
#pragma unroll
        for (int r = 0; r < 4; ++r) qs[r] = (_Float16)(accQ[r] * LOG2E);
        *(half4*)(Qf + tbase) = qs;
    }
    {
        half4 ks;
#pragma unroll
        for (int r = 0; r < 4; ++r) ks[r] = (_Float16)accK[r];
        *(half4*)(Kf + tbase) = ks;
    }
    {
        half4 vs;
#pragma unroll
        for (int r = 0; r < 4; ++r) vs[r] = (_Float16)accV[r];
        const int kt5 = rt >> 1;
        const int cp0 = 8 * g + 4 * (rt & 1);
        *(half4*)(Vf + ((((size_t)b * 64 + kt5) * 4 + dt) * 16 + ql) * 32 + cp0) = vs;
    }
}

// lane-local max of the 8 scores
#define PMAX(s0, s1)                                                         \
    fmaxf(fmaxf(fmaxf(fmaxf(s0[0], s0[1]), s0[2]),                           \
                fmaxf(fmaxf(s0[3], s1[0]), s1[1])),                          \
          fmaxf(s1[2], s1[3]))

// full reduce + rescale for one tile (inside the rare combined branch)
#define RESC(pm, mr, ls, a0, a1, a2, a3)                                     \
    do {                                                                     \
        float pmw = fmaxf(pm, __shfl_xor(pm, 16));                           \
        pmw = fmaxf(pmw, __shfl_xor(pmw, 32));                               \
        const float mnew = fmaxf(mr, pmw);                                   \
        const float fac  = xexp2(mr - mnew);                                 \
        mr = mnew;                                                           \
        ls *= fac;                                                           \
        const int lg = 4 * ((threadIdx.x & 63) >> 4);                        \
        const int lb = (threadIdx.x & 48);                                   \
        const float f0 = __shfl(fac, lb | (lg + 0));                         \
        const float f1 = __shfl(fac, lb | (lg + 1));                         \
        const float f2 = __shfl(fac, lb | (lg + 2));                         \
        const float f3 = __shfl(fac, lb | (lg + 3));                         \
        a0[0] *= f0; a0[1] *= f1; a0[2] *= f2; a0[3] *= f3;                  \
        a1[0] *= f0; a1[1] *= f1; a1[2] *= f2; a1[3] *= f3;                  \
        a2[0] *= f0; a2[1] *= f1; a2[2] *= f2; a2[3] *= f3;                  \
        a3[0] *= f0; a3[1] *= f1; a3[2] *= f2; a3[3] *= f3;                  \
    } while (0)

// exp2 + lsum + f16 pack for one tile (branch-free)
#define EXPPACK(s0, s1, mr, ls, pav)                                         \
    do {                                                                     \
        const float e0 = xexp2(s0[0] - mr), e1 = xexp2(s0[1] - mr);          \
        const float e2 = xexp2(s0[2] - mr), e3 = xexp2(s0[3] - mr);          \
        const float e4 = xexp2(s1[0] - mr), e5 = xexp2(s1[1] - mr);          \
        const float e6 = xexp2(s1[2] - mr), e7 = xexp2(s1[3] - mr);          \
        ls += ((e0 + e1) + (e2 + e3)) + ((e4 + e5) + (e6 + e7));             \
        pav[0] = (_Float16)e0; pav[1] = (_Float16)e1;                        \
        pav[2] = (_Float16)e2; pav[3] = (_Float16)e3;                        \
        pav[4] = (_Float16)e4; pav[5] = (_Float16)e5;                        \
        pav[6] = (_Float16)e6; pav[7] = (_Float16)e7;                        \
    } while (0)

// ---------------------------------------------------------------------------
// Kernel 2: flash attention, FULLY stage-clustered inner loop (R14 structure
// + single combined trigger): 16 QK^T MFMA -> 4 lane-local maxima -> ONE
// trigger branch (was 4) -> 32 clustered exp2 + 4 packs -> 16 clustered PV
// MFMA. Separate dispatch (R15's cooperative fusion spilled to 112 VGPR and
// ran 4x slower -- reverted). launch_bounds(512,1): ~190 VGPR, no spill.
// ---------------------------------------------------------------------------
__global__ __launch_bounds__(512, 1) void attn_kernel(
    const _Float16* __restrict__ Qf, const _Float16* __restrict__ Kf,
    const _Float16* __restrict__ Vf, const float* __restrict__ F,
    float* __restrict__ out)
{
    __shared__ float Ol[8][64][68];    // 139 KB: [split][row][d]
    __shared__ float Ml[8][64];
    __shared__ float Ll[8][64];

    const int lane = threadIdx.x & 63;
    const int wid  = threadIdx.x >> 6;           // 0..7 = key-split
    const int blk  = blockIdx.x;                 // 0..255
    const int b    = blk & 7;                    // XCD-affine batch
    const int tile = blk >> 3;                   // 0..31
    const int ql = lane & 15;
    const int g  = lane >> 4;

    const half8* QfB = (const half8*)Qf + (size_t)b * 16384;  // 128 tiles * 128
    const half8* KfB = (const half8*)Kf + (size_t)b * 16384;
    const half8* VfB = (const half8*)Vf + (size_t)b * 16384;  // 64 tiles * 256

    const half8* qtA = QfB + (size_t)(4 * tile + 0) * 128;
    const half8* qtB = QfB + (size_t)(4 * tile + 1) * 128;
    const half8* qtC = QfB + (size_t)(4 * tile + 2) * 128;
    const half8* qtD = QfB + (size_t)(4 * tile + 3) * 128;
    const half8 qA0 = qtA[g * 16 + ql], qA1 = qtA[(4 + g) * 16 + ql];
    const half8 qB0 = qtB[g * 16 + ql], qB1 = qtB[(4 + g) * 16 + ql];
    const half8 qC0 = qtC[g * 16 + ql], qC1 = qtC[(4 + g) * 16 + ql];
    const half8 qD0 = qtD[g * 16 + ql], qD1 = qtD[(4 + g) * 16 + ql];

    const f32x4 z4 = {0.f, 0.f, 0.f, 0.f};
    f32x4 aA0 = z4, aA1 = z4, aA2 = z4, aA3 = z4;
    f32x4 aB0 = z4, aB1 = z4, aB2 = z4, aB3 = z4;
    f32x4 aC0 = z4, aC1 = z4, aC2 = z4, aC3 = z4;
    f32x4 aD0 = z4, aD1 = z4, aD2 = z4, aD3 = z4;
    float mA = -1e30f, lsA = 0.f;
    float mB = -1e30f, lsB = 0.f;
    float mC = -1e30f, lsC = 0.f;
    float mD = -1e30f, lsD = 0.f;

    const int kb0 = wid << 8;                    // 256 keys per split
    const half8* kA = KfB + (size_t)(kb0 >> 4) * 128 + g * 16 + ql;
    const half8* vA = VfB + (size_t)(kb0 >> 5) * 256 + ql * 4 + g;

    half8 k0lo = kA[0];
    half8 k0hi = kA[64];
    half8 k1lo = kA[128];
    half8 k1hi = kA[192];
    half8 v0 = vA[0];
    half8 v1 = vA[64];
    half8 v2 = vA[128];
    half8 v3 = vA[192];

    for (int it = 0; it < 8; ++it) {
        half8 nk0lo, nk0hi, nk1lo, nk1hi, nv0, nv1, nv2, nv3;
        if (it < 7) {
            nk0lo = kA[256];
            nk0hi = kA[256 + 64];
            nk1lo = kA[256 + 128];
            nk1hi = kA[256 + 192];
            nv0 = vA[256];
            nv1 = vA[256 + 64];
            nv2 = vA[256 + 128];
            nv3 = vA[256 + 192];
        }

        // ---- QK^T phase: 16 MFMAs, branch-free ----
        f32x4 sA0 = z4, sA1 = z4, sB0 = z4, sB1 = z4;
        f32x4 sC0 = z4, sC1 = z4, sD0 = z4, sD1 = z4;
        sA0 = MFMA16(k0lo, qA0, sA0);
        sB0 = MFMA16(k0lo, qB0, sB0);
        sC0 = MFMA16(k0lo, qC0, sC0);
        sD0 = MFMA16(k0lo, qD0, sD0);
        sA1 = MFMA16(k1lo, qA0, sA1);
        sB1 = MFMA16(k1lo, qB0, sB1);
        sC1 = MFMA16(k1lo, qC0, sC1);
        sD1 = MFMA16(k1lo, qD0, sD1);
        sA0 = MFMA16(k0hi, qA1, sA0);
        sB0 = MFMA16(k0hi, qB1, sB0);
        sC0 = MFMA16(k0hi, qC1, sC0);
        sD0 = MFMA16(k0hi, qD1, sD0);
        sA1 = MFMA16(k1hi, qA1, sA1);
        sB1 = MFMA16(k1hi, qB1, sB1);
        sC1 = MFMA16(k1hi, qC1, sC1);
        sD1 = MFMA16(k1hi, qD1, sD1);

        // ---- softmax phase: ONE combined trigger branch ----
        const float pmA = PMAX(sA0, sA1);
        const float pmB = PMAX(sB0, sB1);
        const float pmC = PMAX(sC0, sC1);
        const float pmD = PMAX(sD0, sD1);
        const float trig = fmaxf(fmaxf(pmA - mA, pmB - mB),
                                 fmaxf(pmC - mC, pmD - mD));
        if (__any(trig > 8.0f)) {
            RESC(pmA, mA, lsA, aA0, aA1, aA2, aA3);
            RESC(pmB, mB, lsB, aB0, aB1, aB2, aB3);
            RESC(pmC, mC, lsC, aC0, aC1, aC2, aC3);
            RESC(pmD, mD, lsD, aD0, aD1, aD2, aD3);
        }

        // ---- clustered exp2 + pack ----
        half8 pavA, pavB, pavC, pavD;
        EXPPACK(sA0, sA1, mA, lsA, pavA);
        EXPPACK(sB0, sB1, mB, lsB, pavB);
        EXPPACK(sC0, sC1, mC, lsC, pavC);
        EXPPACK(sD0, sD1, mD, lsD, pavD);

        // ---- clustered PV: 16 MFMAs ----
        aA0 = MFMA16(pavA, v0, aA0);
        aB0 = MFMA16(pavB, v0, aB0);
        aC0 = MFMA16(pavC, v0, aC0);
        aD0 = MFMA16(pavD, v0, aD0);
        aA1 = MFMA16(pavA, v1, aA1);
        aB1 = MFMA16(pavB, v1, aB1);
        aC1 = MFMA16(pavC, v1, aC1);
        aD1 = MFMA16(pavD, v1, aD1);
        aA2 = MFMA16(pavA, v2, aA2);
        aB2 = MFMA16(pavB, v2, aB2);
        aC2 = MFMA16(pavC, v2, aC2);
        aD2 = MFMA16(pavD, v2, aD2);
        aA3 = MFMA16(pavA, v3, aA3);
        aB3 = MFMA16(pavB, v3, aB3);
        aC3 = MFMA16(pavC, v3, aC3);
        aD3 = MFMA16(pavD, v3, aD3);

        if (it < 7) {
            k0lo = nk0lo; k0hi = nk0hi; k1lo = nk1lo; k1hi = nk1hi;
            v0 = nv0; v1 = nv1; v2 = nv2; v3 = nv3;
        }
        kA += 256;
        vA += 256;
    }

    // ---- reduce per-lane lsum partials across the 4 lane-groups ----
    lsA += __shfl_xor(lsA, 16); lsA += __shfl_xor(lsA, 32);
    lsB += __shfl_xor(lsB, 16); lsB += __shfl_xor(lsB, 32);
    lsC += __shfl_xor(lsC, 16); lsC += __shfl_xor(lsC, 32);
    lsD += __shfl_xor(lsD, 16); lsD += __shfl_xor(lsD, 32);

    // ---- write partials to LDS ----
#pragma unroll
    for (int r = 0; r < 4; ++r) {
        Ol[wid][     4 * g + r][ 0 + ql] = aA0[r];
        Ol[wid][     4 * g + r][16 + ql] = aA1[r];
        Ol[wid][     4 * g + r][32 + ql] = aA2[r];
        Ol[wid][     4 * g + r][48 + ql] = aA3[r];
        Ol[wid][16 + 4 * g + r][ 0 + ql] = aB0[r];
        Ol[wid][16 + 4 * g + r][16 + ql] = aB1[r];
        Ol[wid][16 + 4 * g + r][32 + ql] = aB2[r];
        Ol[wid][16 + 4 * g + r][48 + ql] = aB3[r];
        Ol[wid][32 + 4 * g + r][ 0 + ql] = aC0[r];
        Ol[wid][32 + 4 * g + r][16 + ql] = aC1[r];
        Ol[wid][32 + 4 * g + r][32 + ql] = aC2[r];
        Ol[wid][32 + 4 * g + r][48 + ql] = aC3[r];
        Ol[wid][48 + 4 * g + r][ 0 + ql] = aD0[r];
        Ol[wid][48 + 4 * g + r][16 + ql] = aD1[r];
        Ol[wid][48 + 4 * g + r][32 + ql] = aD2[r];
        Ol[wid][48 + 4 * g + r][48 + ql] = aD3[r];
    }
    if (g == 0) {
        Ml[wid][     ql] = mA;  Ll[wid][     ql] = lsA;
        Ml[wid][16 + ql] = mB;  Ll[wid][16 + ql] = lsB;
        Ml[wid][32 + ql] = mC;  Ll[wid][32 + ql] = lsC;
        Ml[wid][48 + ql] = mD;  Ll[wid][48 + ql] = lsD;
    }
    __syncthreads();

    // ---- combine 8 key-splits; 512 threads, one (row, 8-col chunk) each ----
    const int tid = threadIdx.x;
    const int qq  = tid >> 3;                    // 0..63 row within block
    const int d0  = (tid & 7) * 8;

    float mm[8], lv[8];
#pragma unroll
    for (int s = 0; s < 8; ++s) {
        mm[s] = Ml[s][qq];
        lv[s] = Ll[s][qq];
    }
    float ms = mm[0];
#pragma unroll
    for (int s = 1; s < 8; ++s) ms = fmaxf(ms, mm[s]);
    float lt = 0.f;
    f32x4 oa = {0.f, 0.f, 0.f, 0.f};
    f32x4 ob2 = {0.f, 0.f, 0.f, 0.f};
#pragma unroll
    for (int s = 0; s < 8; ++s) {
        const float sc = xexp2(mm[s] - ms);
        lt += lv[s] * sc;
        oa  += *(const f32x4*)(&Ol[s][qq][d0])     * sc;
        ob2 += *(const f32x4*)(&Ol[s][qq][d0 + 4]) * sc;
    }
    const float inv = 1.0f / lt;
    const size_t grow = (size_t)b * T_ + (tile << 6) + qq;
    const f32x4 fr0 = *(const f32x4*)(F + grow * 64 + d0);
    const f32x4 fr1 = *(const f32x4*)(F + grow * 64 + d0 + 4);
    *(f32x4*)(out + grow * 64 + d0)     = oa * inv + fr0;
    *(f32x4*)(out + grow * 64 + d0 + 4) = ob2 * inv + fr1;
}

extern "C" void kernel_launch(void* const* d_in, const int* in_sizes, int n_in,
                              void* d_out, int out_size, void* d_ws, size_t ws_size,
                              hipStream_t stream)
{
    const float* F  = (const float*)d_in[0];
    const float* WM = (const float*)d_in[1];
    const float* WN = (const float*)d_in[2];
    const float* WV = (const float*)d_in[3];
    float* out = (float*)d_out;

    const size_t proj_bytes = (size_t)B_ * T_ * 64 * sizeof(_Float16); // 2 MB
    char* ws = (char*)d_ws;
    _Float16* Qf = (_Float16*)(ws);
    _Float16* Kf = (_Float16*)(ws + proj_bytes);
    _Float16* Vf = (_Float16*)(ws + 2 * proj_bytes);

    hipLaunchKernelGGL(proj_kernel, dim3(B_ * T_ / 16), dim3(256), 0, stream,
                       F, WM, WN, WV, Qf, Kf, Vf);
    hipLaunchKernelGGL(attn_kernel, dim3(B_ * T_ / 64), dim3(512), 0, stream,
                       Qf, Kf, Vf, F, out);
}

// Round 17
// 26.218 us; speedup vs baseline: 4.4556x; 1.0173x over previous
//
#include <hip/hip_runtime.h>
#include <hip/hip_bf16.h>

// Problem constants (fixed by reference): B=8, T=2048, C=64
#define B_ 8
#define T_ 2048
#define LOG2E 1.4426950408889634f

typedef _Float16 half8 __attribute__((ext_vector_type(8)));
typedef _Float16 half4 __attribute__((ext_vector_type(4)));
typedef float f32x4 __attribute__((ext_vector_type(4)));

#define MFMA16(A, Bv, Cv) __builtin_amdgcn_mfma_f32_16x16x32_f16((A), (Bv), (Cv), 0, 0, 0)

__device__ inline float xexp2(float x)
{
    float r;
    asm("v_exp_f32 %0, %1" : "=v"(r) : "v"(x));
    return r;
}

// ---------------------------------------------------------------------------
// Kernel 1: MFMA projections -> fragment-major Q/K/V layouts (R14-verified
// layouts/stores). W-LOAD AMORTIZED: grid 512 x 256 thr; each block owns TWO
// row-tiles and loads its 48 W fragments ONCE (total W-load issue halved vs
// R16's 1024 blocks; W = 48 KB > 32 KB L1, so each block's W re-read was
// L2-latency-bound issue work).
// ---------------------------------------------------------------------------
__global__ __launch_bounds__(256) void proj_kernel(
    const float* __restrict__ F, const float* __restrict__ WM,
    const float* __restrict__ WN, const float* __restrict__ WV,
    _Float16* __restrict__ Qf, _Float16* __restrict__ Kf,
    _Float16* __restrict__ Vf)
{
    const int lane = threadIdx.x & 63;
    const int dt   = threadIdx.x >> 6;            // 0..3 = d-tile
    const int ql = lane & 15;
    const int g  = lane >> 4;
    const int blk = blockIdx.x;                   // 0..511
    const int b   = blk & 7;                      // XCD-affine batch
    const int rt0 = (blk >> 3) * 2;               // first of 2 row-tiles
    const int d = dt * 16 + ql;

    // ---- W fragments, loaded once per block ----
    half8 wq0, wq1, wk0, wk1, wv0, wv1;
#pragma unroll
    for (int j = 0; j < 8; ++j) {
        const int k0 = (8 * g + j) * 64 + d;
        const int k1 = (32 + 8 * g + j) * 64 + d;
        wq0[j] = (_Float16)WM[k0];
        wq1[j] = (_Float16)WM[k1];
        wk0[j] = (_Float16)WN[k0];
        wk1[j] = (_Float16)WN[k1];
        wv0[j] = (_Float16)WV[k0];
        wv1[j] = (_Float16)WV[k1];
    }

#pragma unroll 2
    for (int rr = 0; rr < 2; ++rr) {
        const int rt = rt0 + rr;
        const int rowbase = b * T_ + rt * 16;

        const float* fr = F + (size_t)(rowbase + ql) * 64;
        const f32x4 v00 = *(const f32x4*)(fr + 8 * g);
        const f32x4 v01 = *(const f32x4*)(fr + 8 * g + 4);
        const f32x4 v10 = *(const f32x4*)(fr + 32 + 8 * g);
        const f32x4 v11 = *(const f32x4*)(fr + 32 + 8 * g + 4);
        half8 af0, af1;
#pragma unroll
        for (int j = 0; j < 4; ++j) {
            af0[j]     = (_Float16)v00[j];
            af0[4 + j] = (_Float16)v01[j];
            af1[j]     = (_Float16)v10[j];
            af1[4 + j] = (_Float16)v11[j];
        }

        f32x4 z = {0.f, 0.f, 0.f, 0.f};
        // Q, K swapped: lane = t (row), regs = d
        f32x4 accQ = MFMA16(wq0, af0, z);
        accQ = MFMA16(wq1, af1, accQ);
        f32x4 accK = MFMA16(wk0, af0, z);
        accK = MFMA16(wk1, af1, accK);
        // V unswapped: lane = d, regs = key
        f32x4 accV = MFMA16(af0, wv0, z);
        accV = MFMA16(af1, wv1, accV);

        const int d0 = dt * 16 + 4 * g;
        const int p  = ((d0 >> 5) << 2) | ((d0 >> 3) & 3);
        const size_t tbase =
            (((size_t)b * 128 + rt) * 8 + p) * 128 + ql * 8 + (d0 & 7);
        {
            half4 qs;
#pragma unroll
            for (int r = 0; r < 4; ++r) qs[r] = (_Float16)(accQ[r] * LOG2E);
            *(half4*)(Qf + tbase) = qs;
        }
        {
            half4 ks;
#pragma unroll
            for (int r = 0; r < 4; ++r) ks[r] = (_Float16)accK[r];
            *(half4*)(Kf + tbase) = ks;
        }
        {
            half4 vs;
#pragma unroll
            for (int r = 0; r < 4; ++r) vs[r] = (_Float16)accV[r];
            const int kt5 = rt >> 1;
            const int cp0 = 8 * g + 4 * (rt & 1);
            *(half4*)(Vf + ((((size_t)b * 64 + kt5) * 4 + dt) * 16 + ql) * 32 + cp0) = vs;
        }
    }
}

// lane-local max of the 8 scores
#define PMAX(s0, s1)                                                         \
    fmaxf(fmaxf(fmaxf(fmaxf(s0[0], s0[1]), s0[2]),                           \
                fmaxf(fmaxf(s0[3], s1[0]), s1[1])),                          \
          fmaxf(s1[2], s1[3]))

// full reduce + rescale for one tile (inside the rare combined branch);
// a4 = lsum accumulator (ones-column) scales exactly like the O columns
#define RESC(pm, mr, a0, a1, a2, a3, a4)                                     \
    do {                                                                     \
        float pmw = fmaxf(pm, __shfl_xor(pm, 16));                           \
        pmw = fmaxf(pmw, __shfl_xor(pmw, 32));                               \
        const float mnew = fmaxf(mr, pmw);                                   \
        const float fac  = xexp2(mr - mnew);                                 \
        mr = mnew;                                                           \
        const int lg = 4 * ((threadIdx.x & 63) >> 4);                        \
        const int lb = (threadIdx.x & 48);                                   \
        const float f0 = __shfl(fac, lb | (lg + 0));                         \
        const float f1 = __shfl(fac, lb | (lg + 1));                         \
        const float f2 = __shfl(fac, lb | (lg + 2));                         \
        const float f3 = __shfl(fac, lb | (lg + 3));                         \
        a0[0] *= f0; a0[1] *= f1; a0[2] *= f2; a0[3] *= f3;                  \
        a1[0] *= f0; a1[1] *= f1; a1[2] *= f2; a1[3] *= f3;                  \
        a2[0] *= f0; a2[1] *= f1; a2[2] *= f2; a2[3] *= f3;                  \
        a3[0] *= f0; a3[1] *= f1; a3[2] *= f2; a3[3] *= f3;                  \
        a4[0] *= f0; a4[1] *= f1; a4[2] *= f2; a4[3] *= f3;                  \
    } while (0)

// exp2 + f16 pack for one tile (branch-free; lsum now via ones-column MFMA)
#define EXPPACK(s0, s1, mr, pav)                                             \
    do {                                                                     \
        const float e0 = xexp2(s0[0] - mr), e1 = xexp2(s0[1] - mr);          \
        const float e2 = xexp2(s0[2] - mr), e3 = xexp2(s0[3] - mr);          \
        const float e4 = xexp2(s1[0] - mr), e5 = xexp2(s1[1] - mr);          \
        const float e6 = xexp2(s1[2] - mr), e7 = xexp2(s1[3] - mr);          \
        pav[0] = (_Float16)e0; pav[1] = (_Float16)e1;                        \
        pav[2] = (_Float16)e2; pav[3] = (_Float16)e3;                        \
        pav[4] = (_Float16)e4; pav[5] = (_Float16)e5;                        \
        pav[6] = (_Float16)e6; pav[7] = (_Float16)e7;                        \
    } while (0)

// ---------------------------------------------------------------------------
// Kernel 2: flash attention, stage-clustered inner loop (R16 structure)
// + lsum-via-MFMA: a 5th all-ones B-fragment accumulates per-row sum(P) in
// the accumulator layout (4 extra MFMA/iter replace 28 VALU adds/iter and
// the epilogue's two shfl_xor reduces; lsum becomes per-row exact).
// launch_bounds(512,1): ~205 VGPR, 2 waves/SIMD (VGPR-capped -- 4 waves
// needs <=128 VGPR = 2-tile waves = 2x L1 traffic, measured worse in R11).
// ---------------------------------------------------------------------------
__global__ __launch_bounds__(512, 1) void attn_kernel(
    const _Float16* __restrict__ Qf, const _Float16* __restrict__ Kf,
    const _Float16* __restrict__ Vf, const float* __restrict__ F,
    float* __restrict__ out)
{
    __shared__ float Ol[8][64][68];    // 139 KB: [split][row][d]
    __shared__ float Ml[8][64];
    __shared__ float Ll[8][64];

    const int lane = threadIdx.x & 63;
    const int wid  = threadIdx.x >> 6;           // 0..7 = key-split
    const int blk  = blockIdx.x;                 // 0..255
    const int b    = blk & 7;                    // XCD-affine batch
    const int tile = blk >> 3;                   // 0..31
    const int ql = lane & 15;
    const int g  = lane >> 4;

    const half8* QfB = (const half8*)Qf + (size_t)b * 16384;  // 128 tiles * 128
    const half8* KfB = (const half8*)Kf + (size_t)b * 16384;
    const half8* VfB = (const half8*)Vf + (size_t)b * 16384;  // 64 tiles * 256

    const half8* qtA = QfB + (size_t)(4 * tile + 0) * 128;
    const half8* qtB = QfB + (size_t)(4 * tile + 1) * 128;
    const half8* qtC = QfB + (size_t)(4 * tile + 2) * 128;
    const half8* qtD = QfB + (size_t)(4 * tile + 3) * 128;
    const half8 qA0 = qtA[g * 16 + ql], qA1 = qtA[(4 + g) * 16 + ql];
    const half8 qB0 = qtB[g * 16 + ql], qB1 = qtB[(4 + g) * 16 + ql];
    const half8 qC0 = qtC[g * 16 + ql], qC1 = qtC[(4 + g) * 16 + ql];
    const half8 qD0 = qtD[g * 16 + ql], qD1 = qtD[(4 + g) * 16 + ql];

    half8 vone;
#pragma unroll
    for (int j = 0; j < 8; ++j) vone[j] = (_Float16)1.0f;

    const f32x4 z4 = {0.f, 0.f, 0.f, 0.f};
    f32x4 aA0 = z4, aA1 = z4, aA2 = z4, aA3 = z4, aA4 = z4;
    f32x4 aB0 = z4, aB1 = z4, aB2 = z4, aB3 = z4, aB4 = z4;
    f32x4 aC0 = z4, aC1 = z4, aC2 = z4, aC3 = z4, aC4 = z4;
    f32x4 aD0 = z4, aD1 = z4, aD2 = z4, aD3 = z4, aD4 = z4;
    float mA = -1e30f, mB = -1e30f, mC = -1e30f, mD = -1e30f;

    const int kb0 = wid << 8;                    // 256 keys per split
    const half8* kA = KfB + (size_t)(kb0 >> 4) * 128 + g * 16 + ql;
    const half8* vA = VfB + (size_t)(kb0 >> 5) * 256 + ql * 4 + g;

    half8 k0lo = kA[0];
    half8 k0hi = kA[64];
    half8 k1lo = kA[128];
    half8 k1hi = kA[192];
    half8 v0 = vA[0];
    half8 v1 = vA[64];
    half8 v2 = vA[128];
    half8 v3 = vA[192];

    for (int it = 0; it < 8; ++it) {
        half8 nk0lo, nk0hi, nk1lo, nk1hi, nv0, nv1, nv2, nv3;
        if (it < 7) {
            nk0lo = kA[256];
            nk0hi = kA[256 + 64];
            nk1lo = kA[256 + 128];
            nk1hi = kA[256 + 192];
            nv0 = vA[256];
            nv1 = vA[256 + 64];
            nv2 = vA[256 + 128];
            nv3 = vA[256 + 192];
        }

        // ---- QK^T phase: 16 MFMAs, branch-free ----
        f32x4 sA0 = z4, sA1 = z4, sB0 = z4, sB1 = z4;
        f32x4 sC0 = z4, sC1 = z4, sD0 = z4, sD1 = z4;
        sA0 = MFMA16(k0lo, qA0, sA0);
        sB0 = MFMA16(k0lo, qB0, sB0);
        sC0 = MFMA16(k0lo, qC0, sC0);
        sD0 = MFMA16(k0lo, qD0, sD0);
        sA1 = MFMA16(k1lo, qA0, sA1);
        sB1 = MFMA16(k1lo, qB0, sB1);
        sC1 = MFMA16(k1lo, qC0, sC1);
        sD1 = MFMA16(k1lo, qD0, sD1);
        sA0 = MFMA16(k0hi, qA1, sA0);
        sB0 = MFMA16(k0hi, qB1, sB0);
        sC0 = MFMA16(k0hi, qC1, sC0);
        sD0 = MFMA16(k0hi, qD1, sD0);
        sA1 = MFMA16(k1hi, qA1, sA1);
        sB1 = MFMA16(k1hi, qB1, sB1);
        sC1 = MFMA16(k1hi, qC1, sC1);
        sD1 = MFMA16(k1hi, qD1, sD1);

        // ---- softmax phase: ONE combined trigger branch ----
        const float pmA = PMAX(sA0, sA1);
        const float pmB = PMAX(sB0, sB1);
        const float pmC = PMAX(sC0, sC1);
        const float pmD = PMAX(sD0, sD1);
        const float trig = fmaxf(fmaxf(pmA - mA, pmB - mB),
                                 fmaxf(pmC - mC, pmD - mD));
        if (__any(trig > 8.0f)) {
            RESC(pmA, mA, aA0, aA1, aA2, aA3, aA4);
            RESC(pmB, mB, aB0, aB1, aB2, aB3, aB4);
            RESC(pmC, mC, aC0, aC1, aC2, aC3, aC4);
            RESC(pmD, mD, aD0, aD1, aD2, aD3, aD4);
        }

        // ---- clustered exp2 + pack ----
        half8 pavA, pavB, pavC, pavD;
        EXPPACK(sA0, sA1, mA, pavA);
        EXPPACK(sB0, sB1, mB, pavB);
        EXPPACK(sC0, sC1, mC, pavC);
        EXPPACK(sD0, sD1, mD, pavD);

        // ---- clustered PV: 16 MFMAs + 4 ones-column (lsum) MFMAs ----
        aA0 = MFMA16(pavA, v0, aA0);
        aB0 = MFMA16(pavB, v0, aB0);
        aC0 = MFMA16(pavC, v0, aC0);
        aD0 = MFMA16(pavD, v0, aD0);
        aA1 = MFMA16(pavA, v1, aA1);
        aB1 = MFMA16(pavB, v1, aB1);
        aC1 = MFMA16(pavC, v1, aC1);
        aD1 = MFMA16(pavD, v1, aD1);
        aA2 = MFMA16(pavA, v2, aA2);
        aB2 = MFMA16(pavB, v2, aB2);
        aC2 = MFMA16(pavC, v2, aC2);
        aD2 = MFMA16(pavD, v2, aD2);
        aA3 = MFMA16(pavA, v3, aA3);
        aB3 = MFMA16(pavB, v3, aB3);
        aC3 = MFMA16(pavC, v3, aC3);
        aD3 = MFMA16(pavD, v3, aD3);
        aA4 = MFMA16(pavA, vone, aA4);
        aB4 = MFMA16(pavB, vone, aB4);
        aC4 = MFMA16(pavC, vone, aC4);
        aD4 = MFMA16(pavD, vone, aD4);

        if (it < 7) {
            k0lo = nk0lo; k0hi = nk0hi; k1lo = nk1lo; k1hi = nk1hi;
            v0 = nv0; v1 = nv1; v2 = nv2; v3 = nv3;
        }
        kA += 256;
        vA += 256;
    }

    // ---- write partials to LDS: rows 0..15=A, 16..31=B, 32..47=C, 48..63=D
#pragma unroll
    for (int r = 0; r < 4; ++r) {
        Ol[wid][     4 * g + r][ 0 + ql] = aA0[r];
        Ol[wid][     4 * g + r][16 + ql] = aA1[r];
        Ol[wid][     4 * g + r][32 + ql] = aA2[r];
        Ol[wid][     4 * g + r][48 + ql] = aA3[r];
        Ol[wid][16 + 4 * g + r][ 0 + ql] = aB0[r];
        Ol[wid][16 + 4 * g + r][16 + ql] = aB1[r];
        Ol[wid][16 + 4 * g + r][32 + ql] = aB2[r];
        Ol[wid][16 + 4 * g + r][48 + ql] = aB3[r];
        Ol[wid][32 + 4 * g + r][ 0 + ql] = aC0[r];
        Ol[wid][32 + 4 * g + r][16 + ql] = aC1[r];
        Ol[wid][32 + 4 * g + r][32 + ql] = aC2[r];
        Ol[wid][32 + 4 * g + r][48 + ql] = aC3[r];
        Ol[wid][48 + 4 * g + r][ 0 + ql] = aD0[r];
        Ol[wid][48 + 4 * g + r][16 + ql] = aD1[r];
        Ol[wid][48 + 4 * g + r][32 + ql] = aD2[r];
        Ol[wid][48 + 4 * g + r][48 + ql] = aD3[r];
    }
    if (g == 0) {
        Ml[wid][     ql] = mA;
        Ml[wid][16 + ql] = mB;
        Ml[wid][32 + ql] = mC;
        Ml[wid][48 + ql] = mD;
    }
    if (ql == 0) {
#pragma unroll
        for (int r = 0; r < 4; ++r) {
            Ll[wid][     4 * g + r] = aA4[r];
            Ll[wid][16 + 4 * g + r] = aB4[r];
            Ll[wid][32 + 4 * g + r] = aC4[r];
            Ll[wid][48 + 4 * g + r] = aD4[r];
        }
    }
    __syncthreads();

    // ---- combine 8 key-splits; 512 threads, one (row, 8-col chunk) each ----
    const int tid = threadIdx.x;
    const int qq  = tid >> 3;                    // 0..63 row within block
    const int d0  = (tid & 7) * 8;

    float mm[8], lv[8];
#pragma unroll
    for (int s = 0; s < 8; ++s) {
        mm[s] = Ml[s][qq];
        lv[s] = Ll[s][qq];
    }
    float ms = mm[0];
#pragma unroll
    for (int s = 1; s < 8; ++s) ms = fmaxf(ms, mm[s]);
    float lt = 0.f;
    f32x4 oa = {0.f, 0.f, 0.f, 0.f};
    f32x4 ob2 = {0.f, 0.f, 0.f, 0.f};
#pragma unroll
    for (int s = 0; s < 8; ++s) {
        const float sc = xexp2(mm[s] - ms);
        lt += lv[s] * sc;
        oa  += *(const f32x4*)(&Ol[s][qq][d0])     * sc;
        ob2 += *(const f32x4*)(&Ol[s][qq][d0 + 4]) * sc;
    }
    const float inv = 1.0f / lt;
    const size_t grow = (size_t)b * T_ + (tile << 6) + qq;
    const f32x4 fr0 = *(const f32x4*)(F + grow * 64 + d0);
    const f32x4 fr1 = *(const f32x4*)(F + grow * 64 + d0 + 4);
    *(f32x4*)(out + grow * 64 + d0)     = oa * inv + fr0;
    *(f32x4*)(out + grow * 64 + d0 + 4) = ob2 * inv + fr1;
}

extern "C" void kernel_launch(void* const* d_in, const int* in_sizes, int n_in,
                              void* d_out, int out_size, void* d_ws, size_t ws_size,
                              hipStream_t stream)
{
    const float* F  = (const float*)d_in[0];
    const float* WM = (const float*)d_in[1];
    const float* WN = (const float*)d_in[2];
    const float* WV = (const float*)d_in[3];
    float* out = (float*)d_out;

    const size_t proj_bytes = (size_t)B_ * T_ * 64 * sizeof(_Float16); // 2 MB
    char* ws = (char*)d_ws;
    _Float16* Qf = (_Float16*)(ws);
    _Float16* Kf = (_Float16*)(ws + proj_bytes);
    _Float16* Vf = (_Float16*)(ws + 2 * proj_bytes);

    hipLaunchKernelGGL(proj_kernel, dim3(B_ * T_ / 32), dim3(256), 0, stream,
                       F, WM, WN, WV, Qf, Kf, Vf);
    hipLaunchKernelGGL(attn_kernel, dim3(B_ * T_ / 64), dim3(512), 0, stream,
                       Qf, Kf, Vf, F, out);
}

// Round 18
// 26.167 us; speedup vs baseline: 4.4641x; 1.0019x over previous
//
#include <hip/hip_runtime.h>
#include <hip/hip_bf16.h>

// Problem constants (fixed by reference): B=8, T=2048, C=64
#define B_ 8
#define T_ 2048
#define LOG2E 1.4426950408889634f

typedef _Float16 half8 __attribute__((ext_vector_type(8)));
typedef _Float16 half4 __attribute__((ext_vector_type(4)));
typedef float f32x4 __attribute__((ext_vector_type(4)));

#define MFMA16(A, Bv, Cv) __builtin_amdgcn_mfma_f32_16x16x32_f16((A), (Bv), (Cv), 0, 0, 0)

__device__ inline float xexp2(float x)
{
    float r;
    asm("v_exp_f32 %0, %1" : "=v"(r) : "v"(x));
    return r;
}

// ---------------------------------------------------------------------------
// Kernel 1: MFMA projections -> fragment-major Q/K/V layouts (R17-verified,
// byte-identical): W loaded once per block, two row-tiles per block,
// all stores 8B coalesced.
// ---------------------------------------------------------------------------
__global__ __launch_bounds__(256) void proj_kernel(
    const float* __restrict__ F, const float* __restrict__ WM,
    const float* __restrict__ WN, const float* __restrict__ WV,
    _Float16* __restrict__ Qf, _Float16* __restrict__ Kf,
    _Float16* __restrict__ Vf)
{
    const int lane = threadIdx.x & 63;
    const int dt   = threadIdx.x >> 6;            // 0..3 = d-tile
    const int ql = lane & 15;
    const int g  = lane >> 4;
    const int blk = blockIdx.x;                   // 0..511
    const int b   = blk & 7;                      // XCD-affine batch
    const int rt0 = (blk >> 3) * 2;               // first of 2 row-tiles
    const int d = dt * 16 + ql;

    half8 wq0, wq1, wk0, wk1, wv0, wv1;
#pragma unroll
    for (int j = 0; j < 8; ++j) {
        const int k0 = (8 * g + j) * 64 + d;
        const int k1 = (32 + 8 * g + j) * 64 + d;
        wq0[j] = (_Float16)WM[k0];
        wq1[j] = (_Float16)WM[k1];
        wk0[j] = (_Float16)WN[k0];
        wk1[j] = (_Float16)WN[k1];
        wv0[j] = (_Float16)WV[k0];
        wv1[j] = (_Float16)WV[k1];
    }

#pragma unroll 2
    for (int rr = 0; rr < 2; ++rr) {
        const int rt = rt0 + rr;
        const int rowbase = b * T_ + rt * 16;

        const float* fr = F + (size_t)(rowbase + ql) * 64;
        const f32x4 v00 = *(const f32x4*)(fr + 8 * g);
        const f32x4 v01 = *(const f32x4*)(fr + 8 * g + 4);
        const f32x4 v10 = *(const f32x4*)(fr + 32 + 8 * g);
        const f32x4 v11 = *(const f32x4*)(fr + 32 + 8 * g + 4);
        half8 af0, af1;
#pragma unroll
        for (int j = 0; j < 4; ++j) {
            af0[j]     = (_Float16)v00[j];
            af0[4 + j] = (_Float16)v01[j];
            af1[j]     = (_Float16)v10[j];
            af1[4 + j] = (_Float16)v11[j];
        }

        f32x4 z = {0.f, 0.f, 0.f, 0.f};
        f32x4 accQ = MFMA16(wq0, af0, z);
        accQ = MFMA16(wq1, af1, accQ);
        f32x4 accK = MFMA16(wk0, af0, z);
        accK = MFMA16(wk1, af1, accK);
        f32x4 accV = MFMA16(af0, wv0, z);
        accV = MFMA16(af1, wv1, accV);

        const int d0 = dt * 16 + 4 * g;
        const int p  = ((d0 >> 5) << 2) | ((d0 >> 3) & 3);
        const size_t tbase =
            (((size_t)b * 128 + rt) * 8 + p) * 128 + ql * 8 + (d0 & 7);
        {
            half4 qs;
#pragma unroll
            for (int r = 0; r < 4; ++r) qs[r] = (_Float16)(accQ[r] * LOG2E);
            *(half4*)(Qf + tbase) = qs;
        }
        {
            half4 ks;
#pragma unroll
            for (int r = 0; r < 4; ++r) ks[r] = (_Float16)accK[r];
            *(half4*)(Kf + tbase) = ks;
        }
        {
            half4 vs;
#pragma unroll
            for (int r = 0; r < 4; ++r) vs[r] = (_Float16)accV[r];
            const int kt5 = rt >> 1;
            const int cp0 = 8 * g + 4 * (rt & 1);
            *(half4*)(Vf + ((((size_t)b * 64 + kt5) * 4 + dt) * 16 + ql) * 32 + cp0) = vs;
        }
    }
}

// lane-local max of the 8 scores
#define PMAX(s0, s1)                                                         \
    fmaxf(fmaxf(fmaxf(fmaxf(s0[0], s0[1]), s0[2]),                           \
                fmaxf(fmaxf(s0[3], s1[0]), s1[1])),                          \
          fmaxf(s1[2], s1[3]))

// full reduce + rescale for one tile (inside the rare combined branch);
// a4 = lsum accumulator (ones-column) scales exactly like the O columns
#define RESC(pm, mr, a0, a1, a2, a3, a4)                                     \
    do {                                                                     \
        float pmw = fmaxf(pm, __shfl_xor(pm, 16));                           \
        pmw = fmaxf(pmw, __shfl_xor(pmw, 32));                               \
        const float mnew = fmaxf(mr, pmw);                                   \
        const float fac  = xexp2(mr - mnew);                                 \
        mr = mnew;                                                           \
        const int lg = 4 * ((threadIdx.x & 63) >> 4);                        \
        const int lb = (threadIdx.x & 48);                                   \
        const float f0 = __shfl(fac, lb | (lg + 0));                         \
        const float f1 = __shfl(fac, lb | (lg + 1));                         \
        const float f2 = __shfl(fac, lb | (lg + 2));                         \
        const float f3 = __shfl(fac, lb | (lg + 3));                         \
        a0[0] *= f0; a0[1] *= f1; a0[2] *= f2; a0[3] *= f3;                  \
        a1[0] *= f0; a1[1] *= f1; a1[2] *= f2; a1[3] *= f3;                  \
        a2[0] *= f0; a2[1] *= f1; a2[2] *= f2; a2[3] *= f3;                  \
        a3[0] *= f0; a3[1] *= f1; a3[2] *= f2; a3[3] *= f3;                  \
        a4[0] *= f0; a4[1] *= f1; a4[2] *= f2; a4[3] *= f3;                  \
    } while (0)

// exp2 + f16 pack for one tile (branch-free; lsum via ones-column MFMA)
#define EXPPACK(s0, s1, mr, pav)                                             \
    do {                                                                     \
        const float e0 = xexp2(s0[0] - mr), e1 = xexp2(s0[1] - mr);          \
        const float e2 = xexp2(s0[2] - mr), e3 = xexp2(s0[3] - mr);          \
        const float e4 = xexp2(s1[0] - mr), e5 = xexp2(s1[1] - mr);          \
        const float e6 = xexp2(s1[2] - mr), e7 = xexp2(s1[3] - mr);          \
        pav[0] = (_Float16)e0; pav[1] = (_Float16)e1;                        \
        pav[2] = (_Float16)e2; pav[3] = (_Float16)e3;                        \
        pav[4] = (_Float16)e4; pav[5] = (_Float16)e5;                        \
        pav[6] = (_Float16)e6; pav[7] = (_Float16)e7;                        \
    } while (0)

// ---------------------------------------------------------------------------
// Kernel 2: flash attention (R17 structure) + T5 s_setprio around the two
// MFMA clusters. The schedule is phase-split (QK^T cluster / VALU softmax /
// PV cluster) with 2 waves/SIMD at different phases -- m191's measured
// regime for setprio (+4-7% attn); proj (lockstep GEMM, m190 null) is left
// untouched.
// ---------------------------------------------------------------------------
__global__ __launch_bounds__(512, 1) void attn_kernel(
    const _Float16* __restrict__ Qf, const _Float16* __restrict__ Kf,
    const _Float16* __restrict__ Vf, const float* __restrict__ F,
    float* __restrict__ out)
{
    __shared__ float Ol[8][64][68];    // 139 KB: [split][row][d]
    __shared__ float Ml[8][64];
    __shared__ float Ll[8][64];

    const int lane = threadIdx.x & 63;
    const int wid  = threadIdx.x >> 6;           // 0..7 = key-split
    const int blk  = blockIdx.x;                 // 0..255
    const int b    = blk & 7;                    // XCD-affine batch
    const int tile = blk >> 3;                   // 0..31
    const int ql = lane & 15;
    const int g  = lane >> 4;

    const half8* QfB = (const half8*)Qf + (size_t)b * 16384;  // 128 tiles * 128
    const half8* KfB = (const half8*)Kf + (size_t)b * 16384;
    const half8* VfB = (const half8*)Vf + (size_t)b * 16384;  // 64 tiles * 256

    const half8* qtA = QfB + (size_t)(4 * tile + 0) * 128;
    const half8* qtB = QfB + (size_t)(4 * tile + 1) * 128;
    const half8* qtC = QfB + (size_t)(4 * tile + 2) * 128;
    const half8* qtD = QfB + (size_t)(4 * tile + 3) * 128;
    const half8 qA0 = qtA[g * 16 + ql], qA1 = qtA[(4 + g) * 16 + ql];
    const half8 qB0 = qtB[g * 16 + ql], qB1 = qtB[(4 + g) * 16 + ql];
    const half8 qC0 = qtC[g * 16 + ql], qC1 = qtC[(4 + g) * 16 + ql];
    const half8 qD0 = qtD[g * 16 + ql], qD1 = qtD[(4 + g) * 16 + ql];

    half8 vone;
#pragma unroll
    for (int j = 0; j < 8; ++j) vone[j] = (_Float16)1.0f;

    const f32x4 z4 = {0.f, 0.f, 0.f, 0.f};
    f32x4 aA0 = z4, aA1 = z4, aA2 = z4, aA3 = z4, aA4 = z4;
    f32x4 aB0 = z4, aB1 = z4, aB2 = z4, aB3 = z4, aB4 = z4;
    f32x4 aC0 = z4, aC1 = z4, aC2 = z4, aC3 = z4, aC4 = z4;
    f32x4 aD0 = z4, aD1 = z4, aD2 = z4, aD3 = z4, aD4 = z4;
    float mA = -1e30f, mB = -1e30f, mC = -1e30f, mD = -1e30f;

    const int kb0 = wid << 8;                    // 256 keys per split
    const half8* kA = KfB + (size_t)(kb0 >> 4) * 128 + g * 16 + ql;
    const half8* vA = VfB + (size_t)(kb0 >> 5) * 256 + ql * 4 + g;

    half8 k0lo = kA[0];
    half8 k0hi = kA[64];
    half8 k1lo = kA[128];
    half8 k1hi = kA[192];
    half8 v0 = vA[0];
    half8 v1 = vA[64];
    half8 v2 = vA[128];
    half8 v3 = vA[192];

    for (int it = 0; it < 8; ++it) {
        half8 nk0lo, nk0hi, nk1lo, nk1hi, nv0, nv1, nv2, nv3;
        if (it < 7) {
            nk0lo = kA[256];
            nk0hi = kA[256 + 64];
            nk1lo = kA[256 + 128];
            nk1hi = kA[256 + 192];
            nv0 = vA[256];
            nv1 = vA[256 + 64];
            nv2 = vA[256 + 128];
            nv3 = vA[256 + 192];
        }

        // ---- QK^T phase: 16 MFMAs, branch-free, high wave priority ----
        __builtin_amdgcn_s_setprio(1);
        f32x4 sA0 = z4, sA1 = z4, sB0 = z4, sB1 = z4;
        f32x4 sC0 = z4, sC1 = z4, sD0 = z4, sD1 = z4;
        sA0 = MFMA16(k0lo, qA0, sA0);
        sB0 = MFMA16(k0lo, qB0, sB0);
        sC0 = MFMA16(k0lo, qC0, sC0);
        sD0 = MFMA16(k0lo, qD0, sD0);
        sA1 = MFMA16(k1lo, qA0, sA1);
        sB1 = MFMA16(k1lo, qB0, sB1);
        sC1 = MFMA16(k1lo, qC0, sC1);
        sD1 = MFMA16(k1lo, qD0, sD1);
        sA0 = MFMA16(k0hi, qA1, sA0);
        sB0 = MFMA16(k0hi, qB1, sB0);
        sC0 = MFMA16(k0hi, qC1, sC0);
        sD0 = MFMA16(k0hi, qD1, sD0);
        sA1 = MFMA16(k1hi, qA1, sA1);
        sB1 = MFMA16(k1hi, qB1, sB1);
        sC1 = MFMA16(k1hi, qC1, sC1);
        sD1 = MFMA16(k1hi, qD1, sD1);
        __builtin_amdgcn_s_setprio(0);

        // ---- softmax phase: ONE combined trigger branch ----
        const float pmA = PMAX(sA0, sA1);
        const float pmB = PMAX(sB0, sB1);
        const float pmC = PMAX(sC0, sC1);
        const float pmD = PMAX(sD0, sD1);
        const float trig = fmaxf(fmaxf(pmA - mA, pmB - mB),
                                 fmaxf(pmC - mC, pmD - mD));
        if (__any(trig > 8.0f)) {
            RESC(pmA, mA, aA0, aA1, aA2, aA3, aA4);
            RESC(pmB, mB, aB0, aB1, aB2, aB3, aB4);
            RESC(pmC, mC, aC0, aC1, aC2, aC3, aC4);
            RESC(pmD, mD, aD0, aD1, aD2, aD3, aD4);
        }

        // ---- clustered exp2 + pack ----
        half8 pavA, pavB, pavC, pavD;
        EXPPACK(sA0, sA1, mA, pavA);
        EXPPACK(sB0, sB1, mB, pavB);
        EXPPACK(sC0, sC1, mC, pavC);
        EXPPACK(sD0, sD1, mD, pavD);

        // ---- clustered PV: 20 MFMAs, high wave priority ----
        __builtin_amdgcn_s_setprio(1);
        aA0 = MFMA16(pavA, v0, aA0);
        aB0 = MFMA16(pavB, v0, aB0);
        aC0 = MFMA16(pavC, v0, aC0);
        aD0 = MFMA16(pavD, v0, aD0);
        aA1 = MFMA16(pavA, v1, aA1);
        aB1 = MFMA16(pavB, v1, aB1);
        aC1 = MFMA16(pavC, v1, aC1);
        aD1 = MFMA16(pavD, v1, aD1);
        aA2 = MFMA16(pavA, v2, aA2);
        aB2 = MFMA16(pavB, v2, aB2);
        aC2 = MFMA16(pavC, v2, aC2);
        aD2 = MFMA16(pavD, v2, aD2);
        aA3 = MFMA16(pavA, v3, aA3);
        aB3 = MFMA16(pavB, v3, aB3);
        aC3 = MFMA16(pavC, v3, aC3);
        aD3 = MFMA16(pavD, v3, aD3);
        aA4 = MFMA16(pavA, vone, aA4);
        aB4 = MFMA16(pavB, vone, aB4);
        aC4 = MFMA16(pavC, vone, aC4);
        aD4 = MFMA16(pavD, vone, aD4);
        __builtin_amdgcn_s_setprio(0);

        if (it < 7) {
            k0lo = nk0lo; k0hi = nk0hi; k1lo = nk1lo; k1hi = nk1hi;
            v0 = nv0; v1 = nv1; v2 = nv2; v3 = nv3;
        }
        kA += 256;
        vA += 256;
    }

    // ---- write partials to LDS: rows 0..15=A, 16..31=B, 32..47=C, 48..63=D
#pragma unroll
    for (int r = 0; r < 4; ++r) {
        Ol[wid][     4 * g + r][ 0 + ql] = aA0[r];
        Ol[wid][     4 * g + r][16 + ql] = aA1[r];
        Ol[wid][     4 * g + r][32 + ql] = aA2[r];
        Ol[wid][     4 * g + r][48 + ql] = aA3[r];
        Ol[wid][16 + 4 * g + r][ 0 + ql] = aB0[r];
        Ol[wid][16 + 4 * g + r][16 + ql] = aB1[r];
        Ol[wid][16 + 4 * g + r][32 + ql] = aB2[r];
        Ol[wid][16 + 4 * g + r][48 + ql] = aB3[r];
        Ol[wid][32 + 4 * g + r][ 0 + ql] = aC0[r];
        Ol[wid][32 + 4 * g + r][16 + ql] = aC1[r];
        Ol[wid][32 + 4 * g + r][32 + ql] = aC2[r];
        Ol[wid][32 + 4 * g + r][48 + ql] = aC3[r];
        Ol[wid][48 + 4 * g + r][ 0 + ql] = aD0[r];
        Ol[wid][48 + 4 * g + r][16 + ql] = aD1[r];
        Ol[wid][48 + 4 * g + r][32 + ql] = aD2[r];
        Ol[wid][48 + 4 * g + r][48 + ql] = aD3[r];
    }
    if (g == 0) {
        Ml[wid][     ql] = mA;
        Ml[wid][16 + ql] = mB;
        Ml[wid][32 + ql] = mC;
        Ml[wid][48 + ql] = mD;
    }
    if (ql == 0) {
#pragma unroll
        for (int r = 0; r < 4; ++r) {
            Ll[wid][     4 * g + r] = aA4[r];
            Ll[wid][16 + 4 * g + r] = aB4[r];
            Ll[wid][32 + 4 * g + r] = aC4[r];
            Ll[wid][48 + 4 * g + r] = aD4[r];
        }
    }
    __syncthreads();

    // ---- combine 8 key-splits; 512 threads, one (row, 8-col chunk) each ----
    const int tid = threadIdx.x;
    const int qq  = tid >> 3;                    // 0..63 row within block
    const int d0  = (tid & 7) * 8;

    float mm[8], lv[8];
#pragma unroll
    for (int s = 0; s < 8; ++s) {
        mm[s] = Ml[s][qq];
        lv[s] = Ll[s][qq];
    }
    float ms = mm[0];
#pragma unroll
    for (int s = 1; s < 8; ++s) ms = fmaxf(ms, mm[s]);
    float lt = 0.f;
    f32x4 oa = {0.f, 0.f, 0.f, 0.f};
    f32x4 ob2 = {0.f, 0.f, 0.f, 0.f};
#pragma unroll
    for (int s = 0; s < 8; ++s) {
        const float sc = xexp2(mm[s] - ms);
        lt += lv[s] * sc;
        oa  += *(const f32x4*)(&Ol[s][qq][d0])     * sc;
        ob2 += *(const f32x4*)(&Ol[s][qq][d0 + 4]) * sc;
    }
    const float inv = 1.0f / lt;
    const size_t grow = (size_t)b * T_ + (tile << 6) + qq;
    const f32x4 fr0 = *(const f32x4*)(F + grow * 64 + d0);
    const f32x4 fr1 = *(const f32x4*)(F + grow * 64 + d0 + 4);
    *(f32x4*)(out + grow * 64 + d0)     = oa * inv + fr0;
    *(f32x4*)(out + grow * 64 + d0 + 4) = ob2 * inv + fr1;
}

extern "C" void kernel_launch(void* const* d_in, const int* in_sizes, int n_in,
                              void* d_out, int out_size, void* d_ws, size_t ws_size,
                              hipStream_t stream)
{
    const float* F  = (const float*)d_in[0];
    const float* WM = (const float*)d_in[1];
    const float* WN = (const float*)d_in[2];
    const float* WV = (const float*)d_in[3];
    float* out = (float*)d_out;

    const size_t proj_bytes = (size_t)B_ * T_ * 64 * sizeof(_Float16); // 2 MB
    char* ws = (char*)d_ws;
    _Float16* Qf = (_Float16*)(ws);
    _Float16* Kf = (_Float16*)(ws + proj_bytes);
    _Float16* Vf = (_Float16*)(ws + 2 * proj_bytes);

    hipLaunchKernelGGL(proj_kernel, dim3(B_ * T_ / 32), dim3(256), 0, stream,
                       F, WM, WN, WV, Qf, Kf, Vf);
    hipLaunchKernelGGL(attn_kernel, dim3(B_ * T_ / 64), dim3(512), 0, stream,
                       Qf, Kf, Vf, F, out);
}